// Round 5
// baseline (546.671 us; speedup 1.0000x reference)
//
#include <hip/hip_runtime.h>
#include <hip/hip_fp16.h>
#include <stdint.h>

// ---------------------------------------------------------------------------
// GNN forward: GCN -> SAGE(+res) -> SAGE(+res) -> lin -> GCN
// Strategy: aggregate-first (linearity), CSR built once per call, fused dense
// 64x64 GEMM epilogues, fp16 gather mirror.
// R2: bounded unroll + launch_bounds(256,2) fixed GEMM spill.
// R3: quarter-wave float4 gather (16 rows in flight/wave).
// R4: XCD-sliced scatter + fp16 gather mirror.
// R5: counting-sort bucket scatter for CSR build. k_bucket makes one pass over
//     edges, scattering (src,dst) into 8 dst-slice buckets (contiguous per-block
//     runs, write-once). k_deg2/k_fill2 then read ONLY their slice's bucket
//     (XCD-affine bid&7): edge data read 2x total instead of 8x, deg/csr lines
//     stay in one L2. k_fill2 counts DOWN on deg (cnt array eliminated);
//     k_prep fused into k_scanC. Buckets alias bufA (dead during CSR build).
// ---------------------------------------------------------------------------

typedef unsigned long long ull;

__device__ __forceinline__ void fma4(float4& a, float s, const float4& w){
  a.x = fmaf(s, w.x, a.x);
  a.y = fmaf(s, w.y, a.y);
  a.z = fmaf(s, w.z, a.z);
  a.w = fmaf(s, w.w, a.w);
}

__device__ __forceinline__ ushort4 pack_h4(float4 v){
  ushort4 u;
  u.x = __half_as_ushort(__float2half(v.x));
  u.y = __half_as_ushort(__float2half(v.y));
  u.z = __half_as_ushort(__float2half(v.z));
  u.w = __half_as_ushort(__float2half(v.w));
  return u;
}

__device__ __forceinline__ float4 unpack_h4(ushort4 u){
  return make_float4(__half2float(__ushort_as_half(u.x)),
                     __half2float(__ushort_as_half(u.y)),
                     __half2float(__ushort_as_half(u.z)),
                     __half2float(__ushort_as_half(u.w)));
}

// ---------------- CSR build: bucket scatter ----------------
// 8 slices by dst (slice = dst / SL). Each block owns a contiguous edge chunk;
// pass 1 builds an LDS histogram, one global reservation per slice, pass 2
// scatters packed (src<<32|dst) into per-slice buckets at LDS cursors.

#define NSL 8
#define BKT_BLOCKS 512

__global__ __launch_bounds__(256) void k_bucket(const int* __restrict__ src,
                                                const int* __restrict__ dst,
                                                ull* __restrict__ bkt,
                                                int* __restrict__ bcnt,
                                                int E, int SL, int cap){
  __shared__ int hist[NSL];
  __shared__ int cur[NSL];
  int t = threadIdx.x;
  int chunk = (E + BKT_BLOCKS - 1) / BKT_BLOCKS;
  int e0 = blockIdx.x * chunk;
  int e1 = min(E, e0 + chunk);
  if (t < NSL) hist[t] = 0;
  __syncthreads();
  // pass 1: count
  for (int e = e0 + t; e < e1; e += 256){
    int s = dst[e] / SL;
    atomicAdd(&hist[s], 1);
  }
  __syncthreads();
  if (t < NSL){
    int h = hist[t];
    cur[t] = h ? atomicAdd(&bcnt[t], h) : 0;
  }
  __syncthreads();
  // pass 2: scatter (chunk re-read is L2-hot)
  for (int e = e0 + t; e < e1; e += 256){
    int d = dst[e];
    int s = d / SL;
    int pos = atomicAdd(&cur[s], 1);
    if (pos < cap)
      bkt[(size_t)s * cap + pos] = ((ull)(unsigned)src[e] << 32) | (unsigned)d;
  }
}

// slice-local degree count: group (bid&7) reads only bucket s
__global__ __launch_bounds__(256) void k_deg2(const ull* __restrict__ bkt,
                                              const int* __restrict__ bcnt,
                                              int* __restrict__ deg, int cap){
  int s = blockIdx.x & 7;
  int q = blockIdx.x >> 3;
  int cnt = min(bcnt[s], cap);
  const ull* b = bkt + (size_t)s * cap;
  for (int i = q * 256 + threadIdx.x; i < cnt; i += (1024 / 8) * 256){
    int d = (int)(b[i] & 0xffffffffu);
    atomicAdd(&deg[d], 1);
  }
}

// slice-local fill: deg counts down to 0, csr lines stay in one L2
__global__ __launch_bounds__(256) void k_fill2(const ull* __restrict__ bkt,
                                               const int* __restrict__ bcnt,
                                               const int* __restrict__ offs,
                                               int* __restrict__ deg,
                                               int* __restrict__ csr, int cap){
  int s = blockIdx.x & 7;
  int q = blockIdx.x >> 3;
  int cnt = min(bcnt[s], cap);
  const ull* b = bkt + (size_t)s * cap;
  for (int i = q * 256 + threadIdx.x; i < cnt; i += (1024 / 8) * 256){
    ull pk = b[i];
    int d  = (int)(pk & 0xffffffffu);
    int sr = (int)(pk >> 32);
    int p  = offs[d] + atomicSub(&deg[d], 1) - 1;
    csr[p] = sr;
  }
}

// ---------------- scans (+prep fused into scanC) ----------------

__global__ __launch_bounds__(256) void k_scanA(const int* __restrict__ deg,
                                               int* __restrict__ bsum, int n){
  __shared__ int sm[256];
  int b = blockIdx.x, t = threadIdx.x;
  int base = b * 1024 + t * 4;
  int s = 0;
  #pragma unroll
  for (int u = 0; u < 4; ++u){ int i = base + u; if (i < n) s += deg[i]; }
  sm[t] = s; __syncthreads();
  for (int off = 128; off > 0; off >>= 1){
    if (t < off) sm[t] += sm[t + off];
    __syncthreads();
  }
  if (t == 0) bsum[b] = sm[0];
}

__global__ void k_scanB(const int* __restrict__ bsum, int* __restrict__ bscan,
                        int* __restrict__ offs, int nb, int n){
  if (blockIdx.x == 0 && threadIdx.x == 0){
    int run = 0;
    for (int i = 0; i < nb; ++i){ bscan[i] = run; run += bsum[i]; }
    offs[n] = run;
  }
}

__global__ __launch_bounds__(256) void k_scanC(const int* __restrict__ deg,
                                               const int* __restrict__ bscan,
                                               int* __restrict__ offs,
                                               float* __restrict__ dis,
                                               float* __restrict__ invd, int n){
  __shared__ int sm[256];
  int b = blockIdx.x, t = threadIdx.x;
  int base = b * 1024 + t * 4;
  int v0 = (base + 0 < n) ? deg[base + 0] : 0;
  int v1 = (base + 1 < n) ? deg[base + 1] : 0;
  int v2 = (base + 2 < n) ? deg[base + 2] : 0;
  int v3 = (base + 3 < n) ? deg[base + 3] : 0;
  int ts = v0 + v1 + v2 + v3;
  sm[t] = ts; __syncthreads();
  #pragma unroll
  for (int off = 1; off < 256; off <<= 1){
    int add = (t >= off) ? sm[t - off] : 0;
    __syncthreads();
    sm[t] += add;
    __syncthreads();
  }
  int excl = sm[t] - ts;
  int run = bscan[b] + excl;
  if (base + 0 < n) offs[base + 0] = run; run += v0;
  if (base + 1 < n) offs[base + 1] = run; run += v1;
  if (base + 2 < n) offs[base + 2] = run; run += v2;
  if (base + 3 < n) offs[base + 3] = run; run += v3;
  // fused prep: dis / invd from the deg values already in registers
  #pragma unroll
  for (int u = 0; u < 4; ++u){
    int i = base + u;
    if (i < n){
      float d = (float)((u == 0) ? v0 : (u == 1) ? v1 : (u == 2) ? v2 : v3);
      dis[i]  = rsqrtf(d + 1.0f);       // GCN: deg includes self-loop
      invd[i] = 1.0f / fmaxf(d, 1.0f);  // SAGE mean divisor
    }
  }
}

// ---------------- fp32 -> fp16 convert (layer-1 gather of x) ---------------

__global__ __launch_bounds__(256) void k_f2h(const float* __restrict__ in,
                                             ushort* __restrict__ out, int n4){
  int i = blockIdx.x * 256 + threadIdx.x;
  if (i < n4){
    float4 v = ((const float4*)in)[i];
    ((ushort4*)out)[i] = pack_h4(v);
  }
}

// ---------------- Aggregation: quarter-wave fp16 gather --------------------
// One wave per node. Lane l: group g=l>>4 handles neighbor csr[k+g], features
// (l&15)*4..+3 as ushort4 (8B). Row = 128B. ~12-16 rows in flight per wave.
// MODE 0: GCN  out[i] = dis[i]*sum_j dis[j]*in[j] + dis[i]^2*in[i]
// MODE 1: SAGE out[i] = (sum_j in[j]) / max(deg,1)

template<int MODE>
__global__ __launch_bounds__(256) void k_agg(const ushort* __restrict__ in,
                                             const int* __restrict__ offs,
                                             const int* __restrict__ csr,
                                             const float* __restrict__ dis,
                                             const float* __restrict__ invd,
                                             float* __restrict__ out, int n){
  int node = (blockIdx.x * 256 + threadIdx.x) >> 6;
  if (node >= n) return;
  int lane = threadIdx.x & 63;
  int g    = lane >> 4;          // neighbor sub-group 0..3
  int fl   = (lane & 15) * 4;    // feature chunk
  int s = offs[node], e = offs[node + 1];

  float4 acc = make_float4(0.f, 0.f, 0.f, 0.f);
  #pragma unroll 4
  for (int k = s + g; k < e; k += 4){
    int j = csr[k];
    float4 v = unpack_h4(*(const ushort4*)(in + (size_t)j * 64 + fl));
    if (MODE == 0){
      fma4(acc, dis[j], v);
    } else {
      acc.x += v.x; acc.y += v.y; acc.z += v.z; acc.w += v.w;
    }
  }

  // combine the 4 neighbor-groups (lanes l, l+16, l+32, l+48)
  acc.x += __shfl_xor(acc.x, 16); acc.y += __shfl_xor(acc.y, 16);
  acc.z += __shfl_xor(acc.z, 16); acc.w += __shfl_xor(acc.w, 16);
  acc.x += __shfl_xor(acc.x, 32); acc.y += __shfl_xor(acc.y, 32);
  acc.z += __shfl_xor(acc.z, 32); acc.w += __shfl_xor(acc.w, 32);

  if (g == 0){
    float4 r;
    if (MODE == 0){
      float di = dis[node];
      float4 self = unpack_h4(*(const ushort4*)(in + (size_t)node * 64 + fl));
      float d2 = di * di;
      r.x = di * acc.x + d2 * self.x;
      r.y = di * acc.y + d2 * self.y;
      r.z = di * acc.z + d2 * self.z;
      r.w = di * acc.w + d2 * self.w;
    } else {
      float iv = invd[node];
      r.x = acc.x * iv; r.y = acc.y * iv; r.z = acc.z * iv; r.w = acc.w * iv;
    }
    *(float4*)(out + (size_t)node * 64 + fl) = r;
  }
}

// ---------------- Dense 64x64 GEMM tiles ----------------
// 256 threads, 64-row tile, each thread computes a 4x4 block. Bounded unroll
// (R2). Epilogues optionally mirror the output to fp16 for the next gather.

__device__ __forceinline__ void stage_A(const float* __restrict__ A,
                                        float (*As)[68], int row0, int n, int t){
  #pragma unroll
  for (int u = 0; u < 4; ++u){
    int q = u * 256 + t;
    int r = q >> 4;
    int c = (q & 15) * 4;
    int gr = row0 + r;
    float4 v = make_float4(0.f, 0.f, 0.f, 0.f);
    if (gr < n) v = *(const float4*)(A + (size_t)gr * 64 + c);
    *(float4*)&As[r][c] = v;
  }
}

__device__ __forceinline__ void stage_W(const float* __restrict__ W,
                                        float (*Ws)[64], int t){
  #pragma unroll
  for (int u = 0; u < 4; ++u){
    int q = u * 256 + t;
    int r = q >> 4;
    int c = (q & 15) * 4;
    *(float4*)&Ws[r][c] = *(const float4*)(W + r * 64 + c);
  }
}

__device__ __forceinline__ void tile_mm(const float (*As)[68], const float (*Ws)[64],
                                        float4 acc[4], int r0, int c0){
  #pragma unroll 2
  for (int k0 = 0; k0 < 64; k0 += 4){
    float4 a0 = *(const float4*)&As[r0+0][k0];
    float4 a1 = *(const float4*)&As[r0+1][k0];
    float4 a2 = *(const float4*)&As[r0+2][k0];
    float4 a3 = *(const float4*)&As[r0+3][k0];
    float4 w0 = *(const float4*)&Ws[k0+0][c0];
    float4 w1 = *(const float4*)&Ws[k0+1][c0];
    float4 w2 = *(const float4*)&Ws[k0+2][c0];
    float4 w3 = *(const float4*)&Ws[k0+3][c0];
    fma4(acc[0], a0.x, w0); fma4(acc[0], a0.y, w1); fma4(acc[0], a0.z, w2); fma4(acc[0], a0.w, w3);
    fma4(acc[1], a1.x, w0); fma4(acc[1], a1.y, w1); fma4(acc[1], a1.z, w2); fma4(acc[1], a1.w, w3);
    fma4(acc[2], a2.x, w0); fma4(acc[2], a2.y, w1); fma4(acc[2], a2.z, w2); fma4(acc[2], a2.w, w3);
    fma4(acc[3], a3.x, w0); fma4(acc[3], a3.y, w1); fma4(acc[3], a3.z, w2); fma4(acc[3], a3.w, w3);
  }
}

// out = act(A @ W + bias)  [+ fp16 mirror if outh != nullptr]
template<bool RELU>
__global__ __launch_bounds__(256, 2) void k_gemm1(const float* __restrict__ A,
                                                  const float* __restrict__ W,
                                                  const float* __restrict__ bias,
                                                  float* __restrict__ out,
                                                  ushort* __restrict__ outh, int n){
  __shared__ __align__(16) float As[64][68];
  __shared__ __align__(16) float Ws[64][64];
  int t = threadIdx.x;
  int row0 = blockIdx.x * 64;
  stage_W(W, Ws, t);
  stage_A(A, As, row0, n, t);
  __syncthreads();
  int r0 = (t >> 4) * 4, c0 = (t & 15) * 4;
  float4 b4 = *(const float4*)(bias + c0);
  float4 acc[4] = {b4, b4, b4, b4};
  tile_mm(As, Ws, acc, r0, c0);
  #pragma unroll
  for (int i = 0; i < 4; ++i){
    int gr = row0 + r0 + i;
    if (gr < n){
      float4 v = acc[i];
      if (RELU){
        v.x = fmaxf(v.x, 0.f); v.y = fmaxf(v.y, 0.f);
        v.z = fmaxf(v.z, 0.f); v.w = fmaxf(v.w, 0.f);
      }
      *(float4*)(out + (size_t)gr * 64 + c0) = v;
      if (outh) *(ushort4*)(outh + (size_t)gr * 64 + c0) = pack_h4(v);
    }
  }
}

// out = act(A @ W1 + B @ W2 + bias + B)   (SAGE layer with residual)
template<bool RELU>
__global__ __launch_bounds__(256, 2) void k_gemm_dual(const float* __restrict__ A,
                                                      const float* __restrict__ B,
                                                      const float* __restrict__ W1,
                                                      const float* __restrict__ W2,
                                                      const float* __restrict__ bias,
                                                      float* __restrict__ out,
                                                      ushort* __restrict__ outh, int n){
  __shared__ __align__(16) float As[64][68];
  __shared__ __align__(16) float Ws1[64][64];
  __shared__ __align__(16) float Ws2[64][64];
  int t = threadIdx.x;
  int row0 = blockIdx.x * 64;
  stage_W(W1, Ws1, t);
  stage_W(W2, Ws2, t);
  stage_A(A, As, row0, n, t);
  __syncthreads();
  int r0 = (t >> 4) * 4, c0 = (t & 15) * 4;
  float4 b4 = *(const float4*)(bias + c0);
  float4 acc[4] = {b4, b4, b4, b4};
  tile_mm(As, Ws1, acc, r0, c0);
  __syncthreads();
  stage_A(B, As, row0, n, t);
  __syncthreads();
  tile_mm(As, Ws2, acc, r0, c0);
  #pragma unroll
  for (int i = 0; i < 4; ++i){
    float4 res = *(const float4*)&As[r0 + i][c0];   // B tile still in LDS
    acc[i].x += res.x; acc[i].y += res.y; acc[i].z += res.z; acc[i].w += res.w;
    if (RELU){
      acc[i].x = fmaxf(acc[i].x, 0.f); acc[i].y = fmaxf(acc[i].y, 0.f);
      acc[i].z = fmaxf(acc[i].z, 0.f); acc[i].w = fmaxf(acc[i].w, 0.f);
    }
    int gr = row0 + r0 + i;
    if (gr < n){
      *(float4*)(out + (size_t)gr * 64 + c0) = acc[i];
      if (outh) *(ushort4*)(outh + (size_t)gr * 64 + c0) = pack_h4(acc[i]);
    }
  }
}

// ---------------------------------------------------------------------------

extern "C" void kernel_launch(void* const* d_in, const int* in_sizes, int n_in,
                              void* d_out, int out_size, void* d_ws, size_t ws_size,
                              hipStream_t stream){
  const float* x        = (const float*)d_in[0];
  const int*   ei       = (const int*)  d_in[1];
  const float* gcn1_w   = (const float*)d_in[2];
  const float* gcn1_b   = (const float*)d_in[3];
  const float* sage1_lw = (const float*)d_in[4];
  const float* sage1_lb = (const float*)d_in[5];
  const float* sage1_rw = (const float*)d_in[6];
  const float* sage2_lw = (const float*)d_in[7];
  const float* sage2_lb = (const float*)d_in[8];
  const float* sage2_rw = (const float*)d_in[9];
  const float* lin_w    = (const float*)d_in[10];
  const float* lin_b    = (const float*)d_in[11];
  const float* gcn2_w   = (const float*)d_in[12];
  const float* gcn2_b   = (const float*)d_in[13];
  float* out = (float*)d_out;

  const int n = in_sizes[0] / 64;
  const int E = in_sizes[1] / 2;
  const int* src = ei;
  const int* dst = ei + E;
  const int SL  = (n + NSL - 1) / NSL;   // dst-slice width
  const int cap = E / 4;                  // per-slice bucket capacity (~2x expected)

  // workspace carve (~70 MB); bkt aliases bufA+bufB (dead during CSR build)
  uintptr_t p = (uintptr_t)d_ws;
  auto alloc = [&](size_t b) -> void* {
    p = (p + 255) & ~(uintptr_t)255;
    void* r = (void*)p; p += b; return r;
  };
  float*  bufA = (float*)alloc((size_t)n * 64 * 4);
  float*  bufB = (float*)alloc((size_t)n * 64 * 4);
  ushort* hh   = (ushort*)alloc((size_t)n * 64 * 2);  // fp16 gather mirror
  int*    deg  = (int*)  alloc((size_t)(n + 8) * 4);  // +8: bcnt tail, one memset
  int*    bcnt = deg + n;
  int*    offs = (int*)  alloc((size_t)(n + 1) * 4);
  const int NB = (n + 1023) / 1024;
  int*    bsum  = (int*) alloc((size_t)NB * 4);
  int*    bscan = (int*) alloc((size_t)NB * 4);
  int*    csr   = (int*) alloc((size_t)E * 4);
  float*  dis   = (float*)alloc((size_t)n * 4);
  float*  invd  = (float*)alloc((size_t)n * 4);
  ull*    bkt   = (ull*)bufA;            // 8 * cap * 8B = 20 MB < bufA (25.6 MB)

  hipMemsetAsync(deg, 0, (size_t)(n + 8) * 4, stream);

  const int gAgg = (n + 3) / 4;      // one wave per node, 4 waves/block
  const int gG = (n + 63) / 64;      // 64-row GEMM tiles
  const int gC = (n * 16 + 255) / 256;

  // CSR build: bucket scatter -> slice-local deg -> scan(+prep) -> slice-local fill
  k_bucket<<<BKT_BLOCKS, 256, 0, stream>>>(src, dst, bkt, bcnt, E, SL, cap);
  k_deg2  <<<1024, 256, 0, stream>>>(bkt, bcnt, deg, cap);
  k_scanA <<<NB, 256, 0, stream>>>(deg, bsum, n);
  k_scanB <<<1, 1, 0, stream>>>(bsum, bscan, offs, NB, n);
  k_scanC <<<NB, 256, 0, stream>>>(deg, bscan, offs, dis, invd, n);
  k_fill2 <<<1024, 256, 0, stream>>>(bkt, bcnt, offs, deg, csr, cap);

  // Layer 1: h1 = relu(GCNagg(x) @ gcn1_w + b)           -> d_out (+hh)
  k_f2h<<<gC, 256, 0, stream>>>(x, hh, n * 16);
  k_agg<0><<<gAgg, 256, 0, stream>>>(hh, offs, csr, dis, invd, bufA, n);
  k_gemm1<true><<<gG, 256, 0, stream>>>(bufA, gcn1_w, gcn1_b, out, hh, n);

  // Layer 2: h2 = relu(mean(h1)@Wl + bl + h1@Wr + h1)    -> bufB (+hh)
  k_agg<1><<<gAgg, 256, 0, stream>>>(hh, offs, csr, dis, invd, bufA, n);
  k_gemm_dual<true><<<gG, 256, 0, stream>>>(bufA, out, sage1_lw, sage1_rw, sage1_lb, bufB, hh, n);

  // Layer 3a: t3 = mean(h2)@Wl2 + bl2 + h2@Wr2 + h2      -> d_out
  k_agg<1><<<gAgg, 256, 0, stream>>>(hh, offs, csr, dis, invd, bufA, n);
  k_gemm_dual<false><<<gG, 256, 0, stream>>>(bufA, bufB, sage2_lw, sage2_rw, sage2_lb, out, (ushort*)nullptr, n);

  // Layer 3b: h4 = relu(t3 @ lin_w + lin_b)              -> bufB (+hh)
  k_gemm1<true><<<gG, 256, 0, stream>>>(out, lin_w, lin_b, bufB, hh, n);

  // Layer 4: out = GCNagg(h4) @ gcn2_w + gcn2_b          -> d_out
  k_agg<0><<<gAgg, 256, 0, stream>>>(hh, offs, csr, dis, invd, bufA, n);
  k_gemm1<false><<<gG, 256, 0, stream>>>(bufA, gcn2_w, gcn2_b, out, (ushort*)nullptr, n);
}